// Round 6
// baseline (55.255 us; speedup 1.0000x reference)
//
#include <hip/hip_runtime.h>
#include <hip/hip_bf16.h>
#include <stdint.h>

typedef unsigned short u16;
typedef unsigned int   u32;
typedef unsigned long long u64;

#define N_ROWS 4096
#define DIM    512
#define NT64   64          // N_ROWS / 64 tiles per side
#define NPAIR64 2080       // NT64*(NT64+1)/2
#define MOD3   729         // 3^6
#define NLEV   6           // levels v = 0..5
#define NKS    16          // DIM / 32 k-steps
#define NSLOT  64          // accumulator replication (de-contended atomics)

typedef __attribute__((ext_vector_type(8))) __bf16 bf16x8;
typedef __attribute__((ext_vector_type(4))) float  f32x4;

// ---- workspace layout (byte offsets) ----
// zpack: fragment-packed bf16 (layout proven in R5, absmax 0).
#define WS_ZPK 0
#define WS_SQ  (N_ROWS * DIM * 2)
#define WS_R   (WS_SQ + N_ROWS * 4)
#define WS_ACC (WS_R + N_ROWS * 4)          // float gsum2[64][8]; u32 gcnt2[64][8]

// ---------------------------------------------------------------------------
// Prep: one wave per row. f32 read, RNE->bf16, scatter into fragment-packed
// zpack; row sum-of-squares; idx % 729; block 0 zeroes the 64-slot accums.
// ---------------------------------------------------------------------------
__global__ __launch_bounds__(64)
void prep_kernel(const float* __restrict__ z, const int* __restrict__ idx,
                 u16* __restrict__ zpack, float* __restrict__ sq,
                 int* __restrict__ rres, u32* __restrict__ acczero)
{
    const int row  = blockIdx.x;
    const int lane = threadIdx.x;
    const float4* zr = reinterpret_cast<const float4*>(z + (size_t)row * DIM) + lane * 2;
    float4 v0 = zr[0], v1 = zr[1];
    float f[8] = {v0.x, v0.y, v0.z, v0.w, v1.x, v1.y, v1.z, v1.w};
    float ss = 0.f;
    u16 u[8];
#pragma unroll
    for (int k = 0; k < 8; ++k) {
        ss += f[k] * f[k];
        u32 b = __builtin_bit_cast(u32, f[k]);
        u[k] = (u16)((b + 0x7FFFu + ((b >> 16) & 1u)) >> 16);   // RNE to bf16
    }
    u16* dst = zpack + ((size_t)((row >> 4) * 16 + (lane >> 2)) * 512)
                     + ((lane & 3) * 16 + (row & 15)) * 8;
    *reinterpret_cast<uint4*>(dst) = *reinterpret_cast<const uint4*>(u);
#pragma unroll
    for (int off = 32; off > 0; off >>= 1) ss += __shfl_down(ss, off, 64);
    if (lane == 0) {
        sq[row]   = ss;
        rres[row] = idx[row] % MOD3;   // idx >= 0
    }
    if (row == 0) {
        // zero gsum2[64][8] + gcnt2[64][8] = 1024 dwords
#pragma unroll
        for (int i = 0; i < 16; ++i) acczero[lane + i * 64] = 0u;
    }
}

// ---------------------------------------------------------------------------
// Epilogue (identical math to R5, indices for a 64x64 tile).
// ---------------------------------------------------------------------------
template<bool DIAG>
__device__ __forceinline__ void epilogue_acc(
    const f32x4 (&acc)[4][4], const float* sqI, const float* sqJ,
    const int* rI, const int* rJ, int lane,
    float (&lsum)[NLEV], u64& pcnt)
{
    const int rbase = (lane >> 4) * 4;   // C/D: row = (lane>>4)*4 + q, col = lane&15
    const int cbase = lane & 15;
#pragma unroll
    for (int m = 0; m < 4; ++m) {
        const int il0 = m * 16 + rbase;
#pragma unroll
        for (int n = 0; n < 4; ++n) {
            const int jl  = n * 16 + cbase;
            const float sqj = sqJ[jl];
            const int   rj  = rJ[jl];
#pragma unroll
            for (int q = 0; q < 4; ++q) {
                const int il = il0 + q;
                float d2 = fmaxf(sqI[il] + sqj - 2.0f * acc[m][n][q], 0.f);
                const float dist = __builtin_amdgcn_sqrtf(d2);   // v_sqrt_f32
                int dm = rI[il] - rj;
                dm += (dm >> 31) & MOD3;            // mod 729 into [0,729)
                const u32 x = (u32)dm;
                // v3 valuation capped at 6: 3^t | x <=> x*inv(3^t) <= thr_t
                int v =
                    (x * 2863311531u <= 1431655765u) +   // 3
                    (x *  954437177u <=  477218588u) +   // 9
                    (x * 1749801491u <=  159072862u) +   // 27
                    (x * 2014922929u <=   53024287u) +   // 81
                    (x * 3534952507u <=   17674762u) +   // 243
                    (x * 4041629033u <=    5891587u);    // 729 (x==0 -> 6)
                if (DIAG) {
                    v = (jl > il) ? v : 6;    // same tile: local upper-tri only
                }
                float tv = 1.0f;
                tv = (v == 1) ? (1.f / 3.f)   : tv;
                tv = (v == 2) ? (1.f / 9.f)   : tv;
                tv = (v == 3) ? (1.f / 27.f)  : tv;
                tv = (v == 4) ? (1.f / 81.f)  : tv;
                tv = (v == 5) ? (1.f / 243.f) : tv;
                const float dd  = dist - tv;
                const float sqd = dd * dd;
#pragma unroll
                for (int vv = 0; vv < NLEV; ++vv)
                    lsum[vv] += (v == vv) ? sqd : 0.f;
                pcnt += 1ull << (8 * v);            // 8-bit field per class
            }
        }
    }
}

// ---------------------------------------------------------------------------
// Main: ONE WAVE per block, one 64x64 tile pair (ti <= tj) per block.
// 2080 blocks -> ~8 waves/CU evenly, no barriers, no thread-block tail.
// Fragments register-loaded from zpack (16 B/lane coalesced, L2/L3-resident),
// 2-deep pipeline. sq/rres staged to LDS via global_load_lds (lane*4 pattern);
// one s_waitcnt(0) after the k-loop covers them. NO launch-bounds reg cap:
// ~155 unified regs must NOT spill (R5's 8 MB scratch WRITE_SIZE villain).
// ---------------------------------------------------------------------------
__global__ __launch_bounds__(64)
void pair_kernel(const u16* __restrict__ zpack, const float* __restrict__ sq,
                 const int* __restrict__ rres, float* __restrict__ gsum2,
                 u32* __restrict__ gcnt2)
{
    __shared__ __align__(16) float sqI[64];
    __shared__ __align__(16) float sqJ[64];
    __shared__ __align__(16) int   rI[64];
    __shared__ __align__(16) int   rJ[64];

    const int lane = threadIdx.x;

    // bijective XCD swizzle (2080 = 8 * 260)
    const int wg = (blockIdx.x & 7) * (NPAIR64 / 8) + (blockIdx.x >> 3);
    int t = wg, ti = 0, rem = NT64;
    while (t >= rem) { t -= rem; ++ti; --rem; }
    const int tj = ti + t;
    const int I0 = ti * 64, J0 = tj * 64;

    // stage sq/rres for both 64-row panels: dst = base + lane*4 (linear),
    // src per-lane = base + lane. Consumed only after s_waitcnt(0) below.
    __builtin_amdgcn_global_load_lds(
        (const __attribute__((address_space(1))) u32*)(sq + I0 + lane),
        (__attribute__((address_space(3))) u32*)sqI, 4, 0, 0);
    __builtin_amdgcn_global_load_lds(
        (const __attribute__((address_space(1))) u32*)(sq + J0 + lane),
        (__attribute__((address_space(3))) u32*)sqJ, 4, 0, 0);
    __builtin_amdgcn_global_load_lds(
        (const __attribute__((address_space(1))) u32*)(rres + I0 + lane),
        (__attribute__((address_space(3))) u32*)rI, 4, 0, 0);
    __builtin_amdgcn_global_load_lds(
        (const __attribute__((address_space(1))) u32*)(rres + J0 + lane),
        (__attribute__((address_space(3))) u32*)rJ, 4, 0, 0);

    const int RA = ti * 4;               // A row-group base (16-row units)
    const int RB = tj * 4;               // B row-group base

    f32x4 acc[4][4];
#pragma unroll
    for (int m = 0; m < 4; ++m)
#pragma unroll
        for (int n = 0; n < 4; ++n) acc[m][n] = (f32x4){0.f, 0.f, 0.f, 0.f};

    // frag (R, s) = zpack u16 index ((R*16 + s)*512) + lane*8
    const u16* zl = zpack + lane * 8;

#define LOADF(A, B, s)                                                         \
    {                                                                          \
        _Pragma("unroll")                                                      \
        for (int m = 0; m < 4; ++m) {                                          \
            A[m] = *reinterpret_cast<const bf16x8*>(                           \
                zl + ((size_t)(RA + m) * 16 + (s)) * 512);                     \
            B[m] = *reinterpret_cast<const bf16x8*>(                           \
                zl + ((size_t)(RB + m) * 16 + (s)) * 512);                     \
        }                                                                      \
    }
#define MFMA_ALL(A, B)                                                         \
    {                                                                          \
        _Pragma("unroll")                                                      \
        for (int m = 0; m < 4; ++m)                                            \
            _Pragma("unroll")                                                  \
            for (int n = 0; n < 4; ++n)                                        \
                acc[m][n] = __builtin_amdgcn_mfma_f32_16x16x32_bf16(           \
                    A[m], B[n], acc[m][n], 0, 0, 0);                           \
    }

    bf16x8 aX[4], bX[4], aY[4], bY[4];
    LOADF(aX, bX, 0);
#pragma unroll
    for (int s = 0; s < NKS; s += 2) {
        LOADF(aY, bY, s + 1);
        MFMA_ALL(aX, bX);
        if (s + 2 < NKS) LOADF(aX, bX, s + 2);
        MFMA_ALL(aY, bY);
    }
#undef LOADF
#undef MFMA_ALL

    __builtin_amdgcn_s_waitcnt(0);   // drain global_load_lds before LDS reads

    // ---- fused epilogue (1 wave: no barriers anywhere) ----
    float lsum[NLEV] = {0.f, 0.f, 0.f, 0.f, 0.f, 0.f};
    u64 pcnt = 0ull;
    if (ti == tj) epilogue_acc<true >(acc, sqI, sqJ, rI, rJ, lane, lsum, pcnt);
    else          epilogue_acc<false>(acc, sqI, sqJ, rI, rJ, lane, lsum, pcnt);

    // wave shuffle reduce, then atomics into slot (blockIdx & 63):
    // ~32 blocks/slot -> negligible contention.
    const int slot = (int)(blockIdx.x & (NSLOT - 1));
#pragma unroll
    for (int vv = 0; vv < NLEV; ++vv) {
        float s = lsum[vv];
        u32   c = (u32)((pcnt >> (8 * vv)) & 255ull);
#pragma unroll
        for (int off = 32; off > 0; off >>= 1) {
            s += __shfl_xor(s, off, 64);
            c += __shfl_xor(c, off, 64);
        }
        if (lane == 0) {
            atomicAdd(&gsum2[slot * 8 + vv], s);
            atomicAdd(&gcnt2[slot * 8 + vv], c);
        }
    }
}

// ---------------------------------------------------------------------------
// Finalize: one wave. Lane t owns slot t; shuffle-reduce the 64 slots.
// ---------------------------------------------------------------------------
__global__ __launch_bounds__(64)
void finalize_kernel(const float* __restrict__ gsum2,
                     const u32* __restrict__ gcnt2,
                     float* __restrict__ out)
{
    const int lane = threadIdx.x;
    float s[NLEV];
    u32   c[NLEV];
#pragma unroll
    for (int v = 0; v < NLEV; ++v) {
        s[v] = gsum2[lane * 8 + v];
        c[v] = gcnt2[lane * 8 + v];
    }
#pragma unroll
    for (int v = 0; v < NLEV; ++v) {
#pragma unroll
        for (int off = 32; off > 0; off >>= 1) {
            s[v] += __shfl_xor(s[v], off, 64);
            c[v] += __shfl_xor(c[v], off, 64);
        }
    }
    if (lane == 0) {
        const float w[NLEV] = {1.f, 1.f / 2.f, 1.f / 3.f, 1.f / 4.f, 1.f / 5.f, 1.f / 6.f};
        float total = 0.f, lc = 0.f;
#pragma unroll
        for (int v = 0; v < NLEV; ++v) {
            const float cnt = (float)c[v];
            const float mse = s[v] / fmaxf(cnt, 1.f);
            const bool  use = c[v] >= 2u;
            total += use ? w[v] * mse : 0.f;
            lc    += use ? 1.f : 0.f;
        }
        out[0] = total / fmaxf(lc, 1.f);
    }
}

// ---------------------------------------------------------------------------
extern "C" void kernel_launch(void* const* d_in, const int* in_sizes, int n_in,
                              void* d_out, int out_size, void* d_ws, size_t ws_size,
                              hipStream_t stream)
{
    const float* z   = (const float*)d_in[0];
    const int*   idx = (const int*)d_in[1];
    char* ws = (char*)d_ws;
    u16*   zpk  = (u16*)(ws + WS_ZPK);
    float* sq   = (float*)(ws + WS_SQ);
    int*   rres = (int*)(ws + WS_R);
    float* gsum2 = (float*)(ws + WS_ACC);
    u32*   gcnt2 = (u32*)(ws + WS_ACC + NSLOT * 8 * 4);
    float* out  = (float*)d_out;

    prep_kernel<<<N_ROWS, 64, 0, stream>>>(z, idx, zpk, sq, rres, (u32*)gsum2);
    pair_kernel<<<NPAIR64, 64, 0, stream>>>(zpk, sq, rres, gsum2, gcnt2);
    finalize_kernel<<<1, 64, 0, stream>>>(gsum2, gcnt2, out);
}

// Round 7
// 43.806 us; speedup vs baseline: 1.2614x; 1.2614x over previous
//
#include <hip/hip_runtime.h>
#include <hip/hip_bf16.h>
#include <stdint.h>

typedef unsigned short u16;
typedef unsigned int   u32;
typedef unsigned long long u64;

#define N_ROWS 4096
#define DIM    512
#define NT64   64          // N_ROWS / 64 tiles per side
#define NPAIR64 2080       // NT64*(NT64+1)/2
#define MOD3   729         // 3^6
#define NLEV   6           // levels v = 0..5
#define NKS    16          // DIM / 32 k-steps
#define NSLOT  64          // accumulator replication (de-contended atomics)

typedef __attribute__((ext_vector_type(8))) __bf16 bf16x8;
typedef __attribute__((ext_vector_type(4))) float  f32x4;

// ---- workspace layout (byte offsets) ----
// zpack: fragment-packed bf16 (layout proven in R5/R6, absmax 0).
#define WS_ZPK 0
#define WS_SQ  (N_ROWS * DIM * 2)
#define WS_R   (WS_SQ + N_ROWS * 4)
#define WS_ACC (WS_R + N_ROWS * 4)          // float gsum2[64][8]; u32 gcnt2[64][8]

// ---------------------------------------------------------------------------
// Prep: 1024 blocks x 256 thr; wave w handles row blockIdx*4 + w.
// f32 read, RNE->bf16, scatter into fragment-packed zpack; row sum-of-squares;
// idx % 729; row 0 zeroes the 64-slot accumulators.
// ---------------------------------------------------------------------------
__global__ __launch_bounds__(256)
void prep_kernel(const float* __restrict__ z, const int* __restrict__ idx,
                 u16* __restrict__ zpack, float* __restrict__ sq,
                 int* __restrict__ rres, u32* __restrict__ acczero)
{
    const int lane = threadIdx.x & 63;
    const int row  = blockIdx.x * 4 + (threadIdx.x >> 6);
    const float4* zr = reinterpret_cast<const float4*>(z + (size_t)row * DIM) + lane * 2;
    float4 v0 = zr[0], v1 = zr[1];
    float f[8] = {v0.x, v0.y, v0.z, v0.w, v1.x, v1.y, v1.z, v1.w};
    float ss = 0.f;
    u16 u[8];
#pragma unroll
    for (int k = 0; k < 8; ++k) {
        ss += f[k] * f[k];
        u32 b = __builtin_bit_cast(u32, f[k]);
        u[k] = (u16)((b + 0x7FFFu + ((b >> 16) & 1u)) >> 16);   // RNE to bf16
    }
    u16* dst = zpack + ((size_t)((row >> 4) * 16 + (lane >> 2)) * 512)
                     + ((lane & 3) * 16 + (row & 15)) * 8;
    *reinterpret_cast<uint4*>(dst) = *reinterpret_cast<const uint4*>(u);
#pragma unroll
    for (int off = 32; off > 0; off >>= 1) ss += __shfl_down(ss, off, 64);
    if (lane == 0) {
        sq[row]   = ss;
        rres[row] = idx[row] % MOD3;   // idx >= 0
    }
    if (row == 0) {
        // zero gsum2[64][8] + gcnt2[64][8] = 1024 dwords
#pragma unroll
        for (int i = 0; i < 16; ++i) acczero[lane + i * 64] = 0u;
    }
}

// ---------------------------------------------------------------------------
// Epilogue (verbatim from R6 -- proven absmax 0).
// ---------------------------------------------------------------------------
template<bool DIAG>
__device__ __forceinline__ void epilogue_acc(
    const f32x4 (&acc)[4][4], const float* sqI, const float* sqJ,
    const int* rI, const int* rJ, int lane,
    float (&lsum)[NLEV], u64& pcnt)
{
    const int rbase = (lane >> 4) * 4;   // C/D: row = (lane>>4)*4 + q, col = lane&15
    const int cbase = lane & 15;
#pragma unroll
    for (int m = 0; m < 4; ++m) {
        const int il0 = m * 16 + rbase;
#pragma unroll
        for (int n = 0; n < 4; ++n) {
            const int jl  = n * 16 + cbase;
            const float sqj = sqJ[jl];
            const int   rj  = rJ[jl];
#pragma unroll
            for (int q = 0; q < 4; ++q) {
                const int il = il0 + q;
                float d2 = fmaxf(sqI[il] + sqj - 2.0f * acc[m][n][q], 0.f);
                const float dist = __builtin_amdgcn_sqrtf(d2);   // v_sqrt_f32
                int dm = rI[il] - rj;
                dm += (dm >> 31) & MOD3;            // mod 729 into [0,729)
                const u32 x = (u32)dm;
                // v3 valuation capped at 6: 3^t | x <=> x*inv(3^t) <= thr_t
                int v =
                    (x * 2863311531u <= 1431655765u) +   // 3
                    (x *  954437177u <=  477218588u) +   // 9
                    (x * 1749801491u <=  159072862u) +   // 27
                    (x * 2014922929u <=   53024287u) +   // 81
                    (x * 3534952507u <=   17674762u) +   // 243
                    (x * 4041629033u <=    5891587u);    // 729 (x==0 -> 6)
                if (DIAG) {
                    v = (jl > il) ? v : 6;    // same tile: local upper-tri only
                }
                float tv = 1.0f;
                tv = (v == 1) ? (1.f / 3.f)   : tv;
                tv = (v == 2) ? (1.f / 9.f)   : tv;
                tv = (v == 3) ? (1.f / 27.f)  : tv;
                tv = (v == 4) ? (1.f / 81.f)  : tv;
                tv = (v == 5) ? (1.f / 243.f) : tv;
                const float dd  = dist - tv;
                const float sqd = dd * dd;
#pragma unroll
                for (int vv = 0; vv < NLEV; ++vv)
                    lsum[vv] += (v == vv) ? sqd : 0.f;
                pcnt += 1ull << (8 * v);            // 8-bit field per class
            }
        }
    }
}

// ---------------------------------------------------------------------------
// Main: ONE WAVE per block, one 64x64 tile pair (ti <= tj).
// __launch_bounds__(64, 2): 256-VGPR budget (2 waves/SIMD, matching the
// grid's 2080/1024). Explicit 4-deep static software pipeline (a0..a3/b0..b3,
// 128 VGPR + 64 acc ~= 207 regs): load->use distance = 3 MFMA blocks ~240 cy
// of issue, covering L2 latency. R6's villain was the allocator shrinking the
// pipeline to fit a 120-reg / 4-wave default -> serialized load->MFMA.
// Loads are wave-uniform SGPR base + lane voffset (SALU addressing).
// ---------------------------------------------------------------------------
__global__ __launch_bounds__(64, 2)
void pair_kernel(const u16* __restrict__ zpack, const float* __restrict__ sq,
                 const int* __restrict__ rres, float* __restrict__ gsum2,
                 u32* __restrict__ gcnt2)
{
    __shared__ __align__(16) float sqI[64];
    __shared__ __align__(16) float sqJ[64];
    __shared__ __align__(16) int   rI[64];
    __shared__ __align__(16) int   rJ[64];

    const int lane = threadIdx.x;

    // bijective XCD swizzle (2080 = 8 * 260)
    const int wg = (blockIdx.x & 7) * (NPAIR64 / 8) + (blockIdx.x >> 3);
    int t = wg, ti = 0, rem = NT64;
    while (t >= rem) { t -= rem; ++ti; --rem; }
    const int tj = ti + t;
    const int I0 = ti * 64, J0 = tj * 64;

    // stage sq/rres for both 64-row panels (consumed after s_waitcnt(0) below)
    __builtin_amdgcn_global_load_lds(
        (const __attribute__((address_space(1))) u32*)(sq + I0 + lane),
        (__attribute__((address_space(3))) u32*)sqI, 4, 0, 0);
    __builtin_amdgcn_global_load_lds(
        (const __attribute__((address_space(1))) u32*)(sq + J0 + lane),
        (__attribute__((address_space(3))) u32*)sqJ, 4, 0, 0);
    __builtin_amdgcn_global_load_lds(
        (const __attribute__((address_space(1))) u32*)(rres + I0 + lane),
        (__attribute__((address_space(3))) u32*)rI, 4, 0, 0);
    __builtin_amdgcn_global_load_lds(
        (const __attribute__((address_space(1))) u32*)(rres + J0 + lane),
        (__attribute__((address_space(3))) u32*)rJ, 4, 0, 0);

    const int RA = ti * 4;               // A row-group base (16-row units)
    const int RB = tj * 4;               // B row-group base
    const int loff = lane * 8;           // u16 elements; lane's 16 B slot

    f32x4 acc[4][4];
#pragma unroll
    for (int m = 0; m < 4; ++m)
#pragma unroll
        for (int n = 0; n < 4; ++n) acc[m][n] = (f32x4){0.f, 0.f, 0.f, 0.f};

#define LOADF(A, B, s)                                                         \
    {                                                                          \
        _Pragma("unroll")                                                      \
        for (int m = 0; m < 4; ++m) {                                          \
            const u16* pa = zpack + ((size_t)((RA + m) * 16 + (s)) << 9);      \
            const u16* pb = zpack + ((size_t)((RB + m) * 16 + (s)) << 9);      \
            A[m] = *reinterpret_cast<const bf16x8*>(pa + loff);                \
            B[m] = *reinterpret_cast<const bf16x8*>(pb + loff);                \
        }                                                                      \
    }
#define MFMA_ALL(A, B)                                                         \
    {                                                                          \
        _Pragma("unroll")                                                      \
        for (int m = 0; m < 4; ++m)                                            \
            _Pragma("unroll")                                                  \
            for (int n = 0; n < 4; ++n)                                        \
                acc[m][n] = __builtin_amdgcn_mfma_f32_16x16x32_bf16(           \
                    A[m], B[n], acc[m][n], 0, 0, 0);                           \
    }

    // 4-deep static pipeline: sets rotate a0->a1->a2->a3; all indices
    // compile-time (full unroll) so everything stays in registers (rule #20).
    bf16x8 a0[4], b0[4], a1[4], b1[4], a2[4], b2[4], a3[4], b3[4];
    LOADF(a0, b0, 0);
    LOADF(a1, b1, 1);
    LOADF(a2, b2, 2);
#pragma unroll
    for (int s4 = 0; s4 < NKS; s4 += 4) {
        if (s4 + 3 < NKS) LOADF(a3, b3, s4 + 3);
        MFMA_ALL(a0, b0);
        if (s4 + 4 < NKS) LOADF(a0, b0, s4 + 4);
        MFMA_ALL(a1, b1);
        if (s4 + 5 < NKS) LOADF(a1, b1, s4 + 5);
        MFMA_ALL(a2, b2);
        if (s4 + 6 < NKS) LOADF(a2, b2, s4 + 6);
        MFMA_ALL(a3, b3);
    }
#undef LOADF
#undef MFMA_ALL

    __builtin_amdgcn_s_waitcnt(0);   // drain global_load_lds before LDS reads

    // ---- fused epilogue (1 wave: no barriers anywhere) ----
    float lsum[NLEV] = {0.f, 0.f, 0.f, 0.f, 0.f, 0.f};
    u64 pcnt = 0ull;
    if (ti == tj) epilogue_acc<true >(acc, sqI, sqJ, rI, rJ, lane, lsum, pcnt);
    else          epilogue_acc<false>(acc, sqI, sqJ, rI, rJ, lane, lsum, pcnt);

    // wave shuffle reduce, then atomics into slot (blockIdx & 63)
    const int slot = (int)(blockIdx.x & (NSLOT - 1));
#pragma unroll
    for (int vv = 0; vv < NLEV; ++vv) {
        float s = lsum[vv];
        u32   c = (u32)((pcnt >> (8 * vv)) & 255ull);
#pragma unroll
        for (int off = 32; off > 0; off >>= 1) {
            s += __shfl_xor(s, off, 64);
            c += __shfl_xor(c, off, 64);
        }
        if (lane == 0) {
            atomicAdd(&gsum2[slot * 8 + vv], s);
            atomicAdd(&gcnt2[slot * 8 + vv], c);
        }
    }
}

// ---------------------------------------------------------------------------
// Finalize: one wave. Lane t owns slot t; shuffle-reduce the 64 slots.
// ---------------------------------------------------------------------------
__global__ __launch_bounds__(64)
void finalize_kernel(const float* __restrict__ gsum2,
                     const u32* __restrict__ gcnt2,
                     float* __restrict__ out)
{
    const int lane = threadIdx.x;
    float s[NLEV];
    u32   c[NLEV];
#pragma unroll
    for (int v = 0; v < NLEV; ++v) {
        s[v] = gsum2[lane * 8 + v];
        c[v] = gcnt2[lane * 8 + v];
    }
#pragma unroll
    for (int v = 0; v < NLEV; ++v) {
#pragma unroll
        for (int off = 32; off > 0; off >>= 1) {
            s[v] += __shfl_xor(s[v], off, 64);
            c[v] += __shfl_xor(c[v], off, 64);
        }
    }
    if (lane == 0) {
        const float w[NLEV] = {1.f, 1.f / 2.f, 1.f / 3.f, 1.f / 4.f, 1.f / 5.f, 1.f / 6.f};
        float total = 0.f, lc = 0.f;
#pragma unroll
        for (int v = 0; v < NLEV; ++v) {
            const float cnt = (float)c[v];
            const float mse = s[v] / fmaxf(cnt, 1.f);
            const bool  use = c[v] >= 2u;
            total += use ? w[v] * mse : 0.f;
            lc    += use ? 1.f : 0.f;
        }
        out[0] = total / fmaxf(lc, 1.f);
    }
}

// ---------------------------------------------------------------------------
extern "C" void kernel_launch(void* const* d_in, const int* in_sizes, int n_in,
                              void* d_out, int out_size, void* d_ws, size_t ws_size,
                              hipStream_t stream)
{
    const float* z   = (const float*)d_in[0];
    const int*   idx = (const int*)d_in[1];
    char* ws = (char*)d_ws;
    u16*   zpk  = (u16*)(ws + WS_ZPK);
    float* sq   = (float*)(ws + WS_SQ);
    int*   rres = (int*)(ws + WS_R);
    float* gsum2 = (float*)(ws + WS_ACC);
    u32*   gcnt2 = (u32*)(ws + WS_ACC + NSLOT * 8 * 4);
    float* out  = (float*)d_out;

    prep_kernel<<<N_ROWS / 4, 256, 0, stream>>>(z, idx, zpk, sq, rres, (u32*)gsum2);
    pair_kernel<<<NPAIR64, 64, 0, stream>>>(zpk, sq, rres, gsum2, gcnt2);
    finalize_kernel<<<1, 64, 0, stream>>>(gsum2, gcnt2, out);
}

// Round 8
// 42.072 us; speedup vs baseline: 1.3133x; 1.0412x over previous
//
#include <hip/hip_runtime.h>
#include <hip/hip_bf16.h>
#include <stdint.h>

typedef unsigned short u16;
typedef unsigned int   u32;
typedef unsigned long long u64;

#define N_ROWS 4096
#define DIM    512
#define NT64   64          // N_ROWS / 64 tiles per side
#define NPAIR64 2080       // NT64*(NT64+1)/2
#define MOD3   729         // 3^6
#define NLEV   6           // levels v = 0..5
#define NKS    16          // DIM / 32 k-steps
#define NSLOT  64          // accumulator replication (de-contended atomics)

typedef __attribute__((ext_vector_type(4))) float f32x4;

// ---- workspace layout (byte offsets) ----
// zpack: fragment-packed FP8 e4m3. Block (R, s) for row-group R (16 rows) and
// k-step s (32 k) is 512 B at ((R<<4)+s)*512; lane L's 8 B at offset L*8 hold
// elements row = R*16 + (L&15), k = s*32 + (L>>4)*8 + j (j = 0..7, byte order)
// == the mfma_f32_16x16x32_fp8_fp8 A/B fragment (2 VGPR/lane).
#define WS_ZPK 0
#define WS_SQ  (N_ROWS * DIM)               // zpack is N*D bytes now
#define WS_R   (WS_SQ + N_ROWS * 4)
#define WS_ACC (WS_R + N_ROWS * 4)          // float gsum2[64][8]; u32 gcnt2[64][8]

// ---------------------------------------------------------------------------
// Prep: 1024 blocks x 256 thr; wave w handles row blockIdx*4 + w.
// f32 read, HW packed convert to fp8 e4m3 (v_cvt_pk_fp8_f32), scatter the
// row's 8-byte chunks into fragment-packed zpack; row sum-of-squares (fp32,
// from ORIGINAL z); idx % 729; row 0 zeroes the 64-slot accumulators.
// ---------------------------------------------------------------------------
__global__ __launch_bounds__(256)
void prep_kernel(const float* __restrict__ z, const int* __restrict__ idx,
                 u64* __restrict__ zpack, float* __restrict__ sq,
                 int* __restrict__ rres, u32* __restrict__ acczero)
{
    const int lane = threadIdx.x & 63;
    const int row  = blockIdx.x * 4 + (threadIdx.x >> 6);
    const float4* zr = reinterpret_cast<const float4*>(z + (size_t)row * DIM) + lane * 2;
    float4 v0 = zr[0], v1 = zr[1];
    float f[8] = {v0.x, v0.y, v0.z, v0.w, v1.x, v1.y, v1.z, v1.w};
    float ss = 0.f;
#pragma unroll
    for (int k = 0; k < 8; ++k) ss += f[k] * f[k];
    // pack 8 floats -> 8 fp8 bytes (RNE+sat, OCP e4m3 on gfx950)
    int lo = __builtin_amdgcn_cvt_pk_fp8_f32(f[0], f[1], 0, false);
    lo     = __builtin_amdgcn_cvt_pk_fp8_f32(f[2], f[3], lo, true);
    int hi = __builtin_amdgcn_cvt_pk_fp8_f32(f[4], f[5], 0, false);
    hi     = __builtin_amdgcn_cvt_pk_fp8_f32(f[6], f[7], hi, true);
    const u64 pk = (u64)(u32)lo | ((u64)(u32)hi << 32);
    // lane holds k in [8*lane, 8*lane+8) -> k-step s = lane>>2,
    // dest lane slot L = (lane&3)*16 + (row&15)
    zpack[((size_t)((row >> 4) * 16 + (lane >> 2)) << 6)
          + (lane & 3) * 16 + (row & 15)] = pk;
#pragma unroll
    for (int off = 32; off > 0; off >>= 1) ss += __shfl_down(ss, off, 64);
    if (lane == 0) {
        sq[row]   = ss;
        rres[row] = idx[row] % MOD3;   // idx >= 0
    }
    if (row == 0) {
        // zero gsum2[64][8] + gcnt2[64][8] = 1024 dwords
#pragma unroll
        for (int i = 0; i < 16; ++i) acczero[lane + i * 64] = 0u;
    }
}

// ---------------------------------------------------------------------------
// Epilogue (verbatim from R6/R7 -- proven absmax 0; C/D layout is
// shape-determined, dtype-independent, so unchanged under fp8 operands).
// ---------------------------------------------------------------------------
template<bool DIAG>
__device__ __forceinline__ void epilogue_acc(
    const f32x4 (&acc)[4][4], const float* sqI, const float* sqJ,
    const int* rI, const int* rJ, int lane,
    float (&lsum)[NLEV], u64& pcnt)
{
    const int rbase = (lane >> 4) * 4;   // C/D: row = (lane>>4)*4 + q, col = lane&15
    const int cbase = lane & 15;
#pragma unroll
    for (int m = 0; m < 4; ++m) {
        const int il0 = m * 16 + rbase;
#pragma unroll
        for (int n = 0; n < 4; ++n) {
            const int jl  = n * 16 + cbase;
            const float sqj = sqJ[jl];
            const int   rj  = rJ[jl];
#pragma unroll
            for (int q = 0; q < 4; ++q) {
                const int il = il0 + q;
                float d2 = fmaxf(sqI[il] + sqj - 2.0f * acc[m][n][q], 0.f);
                const float dist = __builtin_amdgcn_sqrtf(d2);   // v_sqrt_f32
                int dm = rI[il] - rj;
                dm += (dm >> 31) & MOD3;            // mod 729 into [0,729)
                const u32 x = (u32)dm;
                // v3 valuation capped at 6: 3^t | x <=> x*inv(3^t) <= thr_t
                int v =
                    (x * 2863311531u <= 1431655765u) +   // 3
                    (x *  954437177u <=  477218588u) +   // 9
                    (x * 1749801491u <=  159072862u) +   // 27
                    (x * 2014922929u <=   53024287u) +   // 81
                    (x * 3534952507u <=   17674762u) +   // 243
                    (x * 4041629033u <=    5891587u);    // 729 (x==0 -> 6)
                if (DIAG) {
                    v = (jl > il) ? v : 6;    // same tile: local upper-tri only
                }
                float tv = 1.0f;
                tv = (v == 1) ? (1.f / 3.f)   : tv;
                tv = (v == 2) ? (1.f / 9.f)   : tv;
                tv = (v == 3) ? (1.f / 27.f)  : tv;
                tv = (v == 4) ? (1.f / 81.f)  : tv;
                tv = (v == 5) ? (1.f / 243.f) : tv;
                const float dd  = dist - tv;
                const float sqd = dd * dd;
#pragma unroll
                for (int vv = 0; vv < NLEV; ++vv)
                    lsum[vv] += (v == vv) ? sqd : 0.f;
                pcnt += 1ull << (8 * v);            // 8-bit field per class
            }
        }
    }
}

// ---------------------------------------------------------------------------
// Main: ONE WAVE per block, one 64x64 tile pair (ti <= tj), fp8 operands.
// __launch_bounds__(64, 2): 256-VGPR budget. 8-deep static software pipeline
// (A/B[8][4] longs = 128 VGPR + 64 acc ~= 220 regs, all indices compile-time
// after full unroll): load->use distance ~7 MFMA blocks (~560 cy of issue),
// covering L3-class latency; fp8 also HALVES fragment bytes (266 -> 133 MB
// aggregate) against the L2/L3 bandwidth bound diagnosed in R7.
// ---------------------------------------------------------------------------
__global__ __launch_bounds__(64, 2)
void pair_kernel(const u64* __restrict__ zpack, const float* __restrict__ sq,
                 const int* __restrict__ rres, float* __restrict__ gsum2,
                 u32* __restrict__ gcnt2)
{
    __shared__ __align__(16) float sqI[64];
    __shared__ __align__(16) float sqJ[64];
    __shared__ __align__(16) int   rI[64];
    __shared__ __align__(16) int   rJ[64];

    const int lane = threadIdx.x;

    // bijective XCD swizzle (2080 = 8 * 260)
    const int wg = (blockIdx.x & 7) * (NPAIR64 / 8) + (blockIdx.x >> 3);
    int t = wg, ti = 0, rem = NT64;
    while (t >= rem) { t -= rem; ++ti; --rem; }
    const int tj = ti + t;
    const int I0 = ti * 64, J0 = tj * 64;

    // stage sq/rres for both 64-row panels (consumed after s_waitcnt(0) below)
    __builtin_amdgcn_global_load_lds(
        (const __attribute__((address_space(1))) u32*)(sq + I0 + lane),
        (__attribute__((address_space(3))) u32*)sqI, 4, 0, 0);
    __builtin_amdgcn_global_load_lds(
        (const __attribute__((address_space(1))) u32*)(sq + J0 + lane),
        (__attribute__((address_space(3))) u32*)sqJ, 4, 0, 0);
    __builtin_amdgcn_global_load_lds(
        (const __attribute__((address_space(1))) u32*)(rres + I0 + lane),
        (__attribute__((address_space(3))) u32*)rI, 4, 0, 0);
    __builtin_amdgcn_global_load_lds(
        (const __attribute__((address_space(1))) u32*)(rres + J0 + lane),
        (__attribute__((address_space(3))) u32*)rJ, 4, 0, 0);

    const int RA = ti * 4;               // A row-group base (16-row units)
    const int RB = tj * 4;               // B row-group base

    f32x4 acc[4][4];
#pragma unroll
    for (int m = 0; m < 4; ++m)
#pragma unroll
        for (int n = 0; n < 4; ++n) acc[m][n] = (f32x4){0.f, 0.f, 0.f, 0.f};

    // frag (R, s) = zpack u64 index ((R*16 + s)*64) + lane
    long A[8][4], B[8][4];

#define LOADF(d, s)                                                            \
    {                                                                          \
        _Pragma("unroll")                                                      \
        for (int m = 0; m < 4; ++m) {                                          \
            A[d][m] = (long)zpack[((size_t)((RA + m) * 16 + (s)) << 6) + lane];\
            B[d][m] = (long)zpack[((size_t)((RB + m) * 16 + (s)) << 6) + lane];\
        }                                                                      \
    }
#define MFMA_ALL(d)                                                            \
    {                                                                          \
        _Pragma("unroll")                                                      \
        for (int m = 0; m < 4; ++m)                                            \
            _Pragma("unroll")                                                  \
            for (int n = 0; n < 4; ++n)                                        \
                acc[m][n] = __builtin_amdgcn_mfma_f32_16x16x32_fp8_fp8(        \
                    A[d][m], B[d][n], acc[m][n], 0, 0, 0);                     \
    }

    // prologue: fill 7 of 8 pipeline sets
#pragma unroll
    for (int s = 0; s < 7; ++s) LOADF(s, s);
    // steady state: issue load for step s+7 before computing step s.
    // Fully unrolled (NKS=16 const) -> all array indices compile-time (rule #20).
#pragma unroll
    for (int s = 0; s < NKS; ++s) {
        if (s + 7 < NKS) LOADF((s + 7) & 7, s + 7);
        MFMA_ALL(s & 7);
    }
#undef LOADF
#undef MFMA_ALL

    __builtin_amdgcn_s_waitcnt(0);   // drain global_load_lds before LDS reads

    // ---- fused epilogue (1 wave: no barriers anywhere) ----
    float lsum[NLEV] = {0.f, 0.f, 0.f, 0.f, 0.f, 0.f};
    u64 pcnt = 0ull;
    if (ti == tj) epilogue_acc<true >(acc, sqI, sqJ, rI, rJ, lane, lsum, pcnt);
    else          epilogue_acc<false>(acc, sqI, sqJ, rI, rJ, lane, lsum, pcnt);

    // wave shuffle reduce, then atomics into slot (blockIdx & 63)
    const int slot = (int)(blockIdx.x & (NSLOT - 1));
#pragma unroll
    for (int vv = 0; vv < NLEV; ++vv) {
        float s = lsum[vv];
        u32   c = (u32)((pcnt >> (8 * vv)) & 255ull);
#pragma unroll
        for (int off = 32; off > 0; off >>= 1) {
            s += __shfl_xor(s, off, 64);
            c += __shfl_xor(c, off, 64);
        }
        if (lane == 0) {
            atomicAdd(&gsum2[slot * 8 + vv], s);
            atomicAdd(&gcnt2[slot * 8 + vv], c);
        }
    }
}

// ---------------------------------------------------------------------------
// Finalize: one wave. Lane t owns slot t; shuffle-reduce the 64 slots.
// ---------------------------------------------------------------------------
__global__ __launch_bounds__(64)
void finalize_kernel(const float* __restrict__ gsum2,
                     const u32* __restrict__ gcnt2,
                     float* __restrict__ out)
{
    const int lane = threadIdx.x;
    float s[NLEV];
    u32   c[NLEV];
#pragma unroll
    for (int v = 0; v < NLEV; ++v) {
        s[v] = gsum2[lane * 8 + v];
        c[v] = gcnt2[lane * 8 + v];
    }
#pragma unroll
    for (int v = 0; v < NLEV; ++v) {
#pragma unroll
        for (int off = 32; off > 0; off >>= 1) {
            s[v] += __shfl_xor(s[v], off, 64);
            c[v] += __shfl_xor(c[v], off, 64);
        }
    }
    if (lane == 0) {
        const float w[NLEV] = {1.f, 1.f / 2.f, 1.f / 3.f, 1.f / 4.f, 1.f / 5.f, 1.f / 6.f};
        float total = 0.f, lc = 0.f;
#pragma unroll
        for (int v = 0; v < NLEV; ++v) {
            const float cnt = (float)c[v];
            const float mse = s[v] / fmaxf(cnt, 1.f);
            const bool  use = c[v] >= 2u;
            total += use ? w[v] * mse : 0.f;
            lc    += use ? 1.f : 0.f;
        }
        out[0] = total / fmaxf(lc, 1.f);
    }
}

// ---------------------------------------------------------------------------
extern "C" void kernel_launch(void* const* d_in, const int* in_sizes, int n_in,
                              void* d_out, int out_size, void* d_ws, size_t ws_size,
                              hipStream_t stream)
{
    const float* z   = (const float*)d_in[0];
    const int*   idx = (const int*)d_in[1];
    char* ws = (char*)d_ws;
    u64*   zpk  = (u64*)(ws + WS_ZPK);
    float* sq   = (float*)(ws + WS_SQ);
    int*   rres = (int*)(ws + WS_R);
    float* gsum2 = (float*)(ws + WS_ACC);
    u32*   gcnt2 = (u32*)(ws + WS_ACC + NSLOT * 8 * 4);
    float* out  = (float*)d_out;

    prep_kernel<<<N_ROWS / 4, 256, 0, stream>>>(z, idx, zpk, sq, rres, (u32*)gsum2);
    pair_kernel<<<NPAIR64, 64, 0, stream>>>(zpk, sq, rres, gsum2, gcnt2);
    finalize_kernel<<<1, 64, 0, stream>>>(gsum2, gcnt2, out);
}